// Round 6
// baseline (347.366 us; speedup 1.0000x reference)
//
#include <hip/hip_runtime.h>

// AttentionXL (TransformerXL relative attention), MI355X gfx950.
// fp32 I/O. Pipeline: weight transposes (bf16) -> 4x bf16 B^T-GEMM (A
// converted in-stage) -> fused MFMA flash-XL.
// Round 6: flash restructure — K/R fragments loaded direct global->VGPR
// (k-contiguous), V staged via column loads + b128 writes (double-buffered,
// ONE barrier/tile), pos2 scratch in bf16. LDS 61KB -> 34.5KB (4 blocks/CU).

typedef unsigned short u16;
typedef short short8 __attribute__((ext_vector_type(8)));
typedef float f32x4 __attribute__((ext_vector_type(4)));

#define CUR 512
#define FULLS 1024
#define BSZ 4
#define NH 16
#define DH 64
#define PREV 512

__device__ __forceinline__ float b2f(u16 u) {
  union { unsigned int i; float f; } x; x.i = ((unsigned int)u) << 16; return x.f;
}
__device__ __forceinline__ u16 f2b(float f) {
  union { float f; unsigned int i; } x; x.f = f;
  unsigned int u = x.i;
  return (u16)((u + 0x7fffu + ((u >> 16) & 1u)) >> 16);
}

__device__ __forceinline__ short8 load8bf(const float* p) {
  const f32x4* q = reinterpret_cast<const f32x4*>(p);
  f32x4 a = q[0], b = q[1];
  short8 r;
#pragma unroll
  for (int e = 0; e < 4; e++) { r[e] = (short)f2b(a[e]); r[e + 4] = (short)f2b(b[e]); }
  return r;
}
__device__ __forceinline__ short8 load8bf(const u16* p) {
  return *reinterpret_cast<const short8*>(p);
}
__device__ __forceinline__ void storeC(u16* C, size_t idx, float v) { C[idx] = f2b(v); }
__device__ __forceinline__ void storeC(float* C, size_t idx, float v) { C[idx] = v; }

// ---------------------------------------------------------------------------
// fp32 W[K x N] -> bf16 WT[N x K]. 64x64 tiles via LDS (pad 66).
// ---------------------------------------------------------------------------
__global__ __launch_bounds__(256)
void transpose_bf16(const float* __restrict__ W, u16* __restrict__ WT, int K, int N) {
  __shared__ u16 ld[64 * 66];
  const int tid = threadIdx.x;
  const int n0 = blockIdx.x * 64, k0 = blockIdx.y * 64;
#pragma unroll
  for (int rep = 0; rep < 16; rep++) {
    int idx = tid + 256 * rep;
    int kk = idx >> 6, nn = idx & 63;
    ld[kk * 66 + nn] = f2b(W[(size_t)(k0 + kk) * N + n0 + nn]);
  }
  __syncthreads();
#pragma unroll
  for (int rep = 0; rep < 16; rep++) {
    int idx = tid + 256 * rep;
    int nn = idx >> 6, kk = idx & 63;
    WT[(size_t)(n0 + nn) * K + k0 + kk] = ld[kk * 66 + nn];
  }
}

// ---------------------------------------------------------------------------
// GEMM (B^T form): C[M,N] = A[M,K] @ BT[N,K]^T + bias[N].
// A fp32 or bf16 (converted in-stage); BT bf16 k-contiguous; C fp32 or bf16.
// 128x128 tile, BK=64, 4 waves (2x2).
// ---------------------------------------------------------------------------
template <typename AT, typename OT>
__global__ __launch_bounds__(256, 2)
void gemm_bt(const AT* __restrict__ A, const u16* __restrict__ BT,
             const float* __restrict__ bias, OT* __restrict__ C,
             int M, int N, int K)
{
  __shared__ __align__(16) short at[8192];  // [(mc*2+kc)][qd*16+mll][8]
  __shared__ __align__(16) short bt[8192];  // [(nc*2+kc)][qd*16+nl][8]

  const int tid = threadIdx.x;
  const int lane = tid & 63, w = tid >> 6;
  const int wr = w >> 1, wc = w & 1;
  const int quad = lane >> 4, ml = lane & 15;
  const int row0 = blockIdx.y * 128, col0 = blockIdx.x * 128;

  f32x4 acc[4][4];
  const f32x4 fzero = {0.f, 0.f, 0.f, 0.f};
#pragma unroll
  for (int i = 0; i < 4; i++)
#pragma unroll
    for (int j = 0; j < 4; j++) acc[i][j] = fzero;

  for (int k0 = 0; k0 < K; k0 += 64) {
    __syncthreads();
#pragma unroll
    for (int cc = 0; cc < 4; cc++) {
      int c = tid + 256 * cc;
      int m = c >> 3, oct = c & 7;
      short8 val = load8bf(A + (size_t)(row0 + m) * K + k0 + oct * 8);
      int mc = m >> 4, mll = m & 15, kc = oct >> 2, qd = oct & 3;
      *reinterpret_cast<short8*>(at + (((mc * 2 + kc) * 64) + qd * 16 + mll) * 8) = val;
    }
#pragma unroll
    for (int cc = 0; cc < 4; cc++) {
      int c = tid + 256 * cc;
      int n = c >> 3, oct = c & 7;
      short8 val = *reinterpret_cast<const short8*>(BT + (size_t)(col0 + n) * K + k0 + oct * 8);
      int nc = n >> 4, nl = n & 15, kc = oct >> 2, qd = oct & 3;
      *reinterpret_cast<short8*>(bt + (((nc * 2 + kc) * 64) + qd * 16 + nl) * 8) = val;
    }
    __syncthreads();

    short8 af[4][2], bf[4][2];
#pragma unroll
    for (int mc = 0; mc < 4; mc++)
#pragma unroll
      for (int kc = 0; kc < 2; kc++)
        af[mc][kc] = *reinterpret_cast<const short8*>(at + ((((wr * 4 + mc) * 2 + kc) * 64) + lane) * 8);
#pragma unroll
    for (int nc = 0; nc < 4; nc++)
#pragma unroll
      for (int kc = 0; kc < 2; kc++)
        bf[nc][kc] = *reinterpret_cast<const short8*>(bt + ((((wc * 4 + nc) * 2 + kc) * 64) + lane) * 8);

#pragma unroll
    for (int mc = 0; mc < 4; mc++)
#pragma unroll
      for (int nc = 0; nc < 4; nc++)
#pragma unroll
        for (int kc = 0; kc < 2; kc++)
          acc[mc][nc] = __builtin_amdgcn_mfma_f32_16x16x32_bf16(af[mc][kc], bf[nc][kc], acc[mc][nc], 0, 0, 0);
  }

#pragma unroll
  for (int nc = 0; nc < 4; nc++) {
    int col = col0 + wc * 64 + nc * 16 + ml;
    float bv = bias[col];
#pragma unroll
    for (int mc = 0; mc < 4; mc++) {
#pragma unroll
      for (int reg = 0; reg < 4; reg++) {
        int row = row0 + wr * 64 + mc * 16 + quad * 4 + reg;
        storeC(C, (size_t)row * N + col, acc[mc][nc][reg] + bv);
      }
    }
  }
}

// ---------------------------------------------------------------------------
// Fused MFMA flash attention, TransformerXL relative position.
// Block = 256 (4 waves) per (i-tile 64, b, h); wave w owns rows i0+16w..+15.
// K and R fragments: direct global->VGPR short8 loads (k-contiguous, L2-hot).
// V: cooperative column-load staging into double-buffered LDS (one barrier
// per tile). pos2 strip spilled as bf16 per-wave; P via per-wave LDS.
// ---------------------------------------------------------------------------
__global__ __launch_bounds__(256, 4)
void flash_xl(const u16* __restrict__ q, const u16* __restrict__ kv,
              const u16* __restrict__ r, const float* __restrict__ u,
              const float* __restrict__ v, u16* __restrict__ av)
{
  __shared__ __align__(16) short vt[2][4096];  // [buf][kc(2)][quad(4)][d(64)][jj(8)]
  __shared__ u16 pos2w[4][16 * 84];            // per-wave pos2 (bf16), row stride 84
  __shared__ __align__(16) short pt[4][1024];  // per-wave P in A-frag order

  const int tid = threadIdx.x, lane = tid & 63, w = tid >> 6;
  const int quad = lane >> 4, ml = lane & 15;
  const int it = blockIdx.x, b = blockIdx.y, h = blockIdx.z;
  const int i0 = it * 64;

  const u16* kvK = kv + (size_t)b * 2048 + h * 64;          // + jg*8192 + d
  const u16* kvV = kv + (size_t)b * 2048 + 1024 + h * 64;
  const u16* rh  = r + h * 64;                               // + rel*1024 + d

  // Q fragments (A-operand): rows i0 + w*16 + ml, +u (content) / +v (position)
  short8 qu[2], qvf[2];
  {
    int ig = i0 + w * 16 + ml;
#pragma unroll
    for (int kc = 0; kc < 2; kc++) {
      int dbase = kc * 32 + quad * 8;
      short8 qq = *reinterpret_cast<const short8*>(q + ((size_t)ig * BSZ + b) * 1024 + h * 64 + dbase);
      const f32x4* up = reinterpret_cast<const f32x4*>(u + h * 64 + dbase);
      const f32x4* vp = reinterpret_cast<const f32x4*>(v + h * 64 + dbase);
      f32x4 u0 = up[0], u1 = up[1], v0 = vp[0], v1 = vp[1];
#pragma unroll
      for (int e = 0; e < 8; e++) {
        float qf = b2f((u16)qq[e]);
        float uu = (e < 4) ? u0[e] : u1[e - 4];
        float vv = (e < 4) ? v0[e] : v1[e - 4];
        qu[kc][e]  = (short)f2b(qf + uu);
        qvf[kc][e] = (short)f2b(qf + vv);
      }
    }
  }

  const f32x4 fzero = {0.f, 0.f, 0.f, 0.f};
  f32x4 o_acc[4];
#pragma unroll
  for (int i = 0; i < 4; i++) o_acc[i] = fzero;
  float m_run[4], l_run[4];
#pragma unroll
  for (int i = 0; i < 4; i++) { m_run[i] = -1e30f; l_run[i] = 0.f; }

  const int ntiles = it + 9;  // covers j <= i0+575 >= max valid j = i0+63+512
  for (int t = 0; t < ntiles; t++) {
    const int j0 = t * 64;
    const int relbase = j0 - i0 + 448;  // >= 0
    const int buf = t & 1;

    // ---- stage V tile: thread (wave w, lane=d) loads 16 j-rows of column d
    // (each load instruction: 64 consecutive u16 = 128B coalesced), packs two
    // short8 k-groups, writes two b128 in B-frag order [kc][quad][d][jj].
    {
      const int kcw = w >> 1, qbase = (w & 1) * 2;
      short8 g0, g1;
#pragma unroll
      for (int s = 0; s < 8; s++)
        g0[s] = (short)kvV[(size_t)(j0 + w * 16 + s) * 8192 + lane];
#pragma unroll
      for (int s = 0; s < 8; s++)
        g1[s] = (short)kvV[(size_t)(j0 + w * 16 + 8 + s) * 8192 + lane];
      *reinterpret_cast<short8*>(vt[buf] + ((kcw * 4 + qbase) * 64 + lane) * 8) = g0;
      *reinterpret_cast<short8*>(vt[buf] + ((kcw * 4 + qbase + 1) * 64 + lane) * 8) = g1;
    }
    __syncthreads();  // single barrier per tile (write->barrier->read; dbuf)

    // ---- content scores: K fragments direct from global (k-contiguous)
    f32x4 sc[4];
#pragma unroll
    for (int nc = 0; nc < 4; nc++) {
      sc[nc] = fzero;
#pragma unroll
      for (int kc = 0; kc < 2; kc++) {
        short8 kf = *reinterpret_cast<const short8*>(
            kvK + (size_t)(j0 + nc * 16 + ml) * 8192 + kc * 32 + quad * 8);
        sc[nc] = __builtin_amdgcn_mfma_f32_16x16x32_bf16(qu[kc], kf, sc[nc], 0, 0, 0);
      }
    }

    // ---- position strip: R fragments direct from global; wave w covers
    // strip chunks (3-w)..(7-w); output cols = chunk*16 + ml.
    f32x4 p2[5];
#pragma unroll
    for (int nc2 = 0; nc2 < 5; nc2++) {
      p2[nc2] = fzero;
      int rel = relbase + ((3 - w) + nc2) * 16 + ml;
      if (rel > 1023) rel = 1023;  // masked region
      const u16* rp = rh + (size_t)rel * 1024;
#pragma unroll
      for (int kc = 0; kc < 2; kc++) {
        short8 rf = *reinterpret_cast<const short8*>(rp + kc * 32 + quad * 8);
        p2[nc2] = __builtin_amdgcn_mfma_f32_16x16x32_bf16(qvf[kc], rf, p2[nc2], 0, 0, 0);
      }
    }
    // spill pos2 (C layout) as bf16 for the row-dependent diagonal gather
#pragma unroll
    for (int nc2 = 0; nc2 < 5; nc2++)
#pragma unroll
      for (int reg = 0; reg < 4; reg++)
        pos2w[w][(quad * 4 + reg) * 84 + nc2 * 16 + ml] = f2b(p2[nc2][reg]);

    // ---- assemble S + mask + online softmax
    float pv_[4][4];
    float tmax[4] = {-1e30f, -1e30f, -1e30f, -1e30f};
#pragma unroll
    for (int nc = 0; nc < 4; nc++) {
      int jl = nc * 16 + ml;
#pragma unroll
      for (int reg = 0; reg < 4; reg++) {
        int rowl = quad * 4 + reg;
        int rrw = jl - rowl + 15;  // in [0,78]
        float s = sc[nc][reg] + b2f(pos2w[w][rowl * 84 + rrw]);
        s *= 0.125f;  // 1/sqrt(64)
        int ig = i0 + w * 16 + rowl;
        int jg = j0 + jl;
        if (jg > ig + PREV) s = -1e30f;
        pv_[nc][reg] = s;
        tmax[reg] = fmaxf(tmax[reg], s);
      }
    }
#pragma unroll
    for (int reg = 0; reg < 4; reg++) {
      float tm = tmax[reg];
#pragma unroll
      for (int off = 1; off < 16; off <<= 1) tm = fmaxf(tm, __shfl_xor(tm, off, 64));
      float mnew = fmaxf(m_run[reg], tm);
      float alpha = __expf(m_run[reg] - mnew);
      float rs = 0.f;
#pragma unroll
      for (int nc = 0; nc < 4; nc++) {
        float p = __expf(pv_[nc][reg] - mnew);
        pv_[nc][reg] = p;
        rs += p;
      }
#pragma unroll
      for (int off = 1; off < 16; off <<= 1) rs += __shfl_xor(rs, off, 64);
      l_run[reg] = l_run[reg] * alpha + rs;
      m_run[reg] = mnew;
#pragma unroll
      for (int nc = 0; nc < 4; nc++) o_acc[nc][reg] *= alpha;
    }

    // ---- P (C layout) -> bf16 A-frag via per-wave LDS transpose
    // k-mapping: element e of pf[kc] at lane(quad,ml) is jl = kc*32+quad*8+e
#pragma unroll
    for (int nc = 0; nc < 4; nc++) {
      int jl = nc * 16 + ml;
      int kc = nc >> 1, qdj = (jl >> 3) & 3, jj = ml & 7;
#pragma unroll
      for (int reg = 0; reg < 4; reg++) {
        int rowl = quad * 4 + reg;
        pt[w][(kc * 64 + qdj * 16 + rowl) * 8 + jj] = (short)f2b(pv_[nc][reg]);
      }
    }
    short8 pf[2];
    pf[0] = *reinterpret_cast<const short8*>(pt[w] + (0 * 64 + lane) * 8);
    pf[1] = *reinterpret_cast<const short8*>(pt[w] + (1 * 64 + lane) * 8);

    // ---- PV accumulate: V B-frag from LDS, same k-mapping (jl = kc*32+quad*8+e)
#pragma unroll
    for (int ncd = 0; ncd < 4; ncd++)
#pragma unroll
      for (int kc = 0; kc < 2; kc++) {
        short8 vf = *reinterpret_cast<const short8*>(
            vt[buf] + ((kc * 4 + quad) * 64 + ncd * 16 + ml) * 8);
        o_acc[ncd] = __builtin_amdgcn_mfma_f32_16x16x32_bf16(pf[kc], vf, o_acc[ncd], 0, 0, 0);
      }
  }

  // ---- normalize and write attn_vec
  float inv[4];
#pragma unroll
  for (int reg = 0; reg < 4; reg++) inv[reg] = 1.0f / l_run[reg];
#pragma unroll
  for (int ncd = 0; ncd < 4; ncd++) {
#pragma unroll
    for (int reg = 0; reg < 4; reg++) {
      int rowl = quad * 4 + reg;
      int ig = i0 + w * 16 + rowl;
      av[((size_t)ig * BSZ + b) * 1024 + h * 64 + ncd * 16 + ml] = f2b(o_acc[ncd][reg] * inv[reg]);
    }
  }
}

// ---------------------------------------------------------------------------
extern "C" void kernel_launch(void* const* d_in, const int* in_sizes, int n_in,
                              void* d_out, int out_size, void* d_ws, size_t ws_size,
                              hipStream_t stream) {
  (void)in_sizes; (void)n_in; (void)out_size; (void)ws_size;

  const float* inputs  = (const float*)d_in[0];   // (512,4,1024)
  const float* pos_emb = (const float*)d_in[1];   // (1024,1,1024)
  const float* full_in = (const float*)d_in[2];   // (1024,4,1024)
  const float* u       = (const float*)d_in[3];   // (16,64)
  const float* v       = (const float*)d_in[4];   // (16,64)
  const float* W_kv    = (const float*)d_in[5];   // (1024,2048)
  const float* b_kv    = (const float*)d_in[6];   // (2048,)
  const float* W_q     = (const float*)d_in[7];   // (1024,1024)
  const float* b_q     = (const float*)d_in[8];
  const float* W_pos   = (const float*)d_in[9];   // (1024,1024)
  const float* b_pos   = (const float*)d_in[10];
  const float* W_proj  = (const float*)d_in[11];  // (1024,1024)
  const float* b_proj  = (const float*)d_in[12];
  // d_in[13] = mask (bool) — recomputed analytically (j > i + 512)
  float* out = (float*)d_out;

  char* ws = (char*)d_ws;
  u16* kv    = (u16*)(ws);                  // 16 MB: 4096x2048
  u16* qq    = (u16*)(ws + (16u << 20));    //  4 MB: 2048x1024
  u16* rr    = (u16*)(ws + (20u << 20));    //  2 MB: 1024x1024
  u16* av    = (u16*)(ws + (22u << 20));    //  4 MB: 2048x1024
  u16* WkvT  = (u16*)(ws + (26u << 20));    //  4 MB: 2048x1024
  u16* WqT   = (u16*)(ws + (30u << 20));    //  2 MB: 1024x1024
  u16* WposT = (u16*)(ws + (32u << 20));    //  2 MB: 1024x1024
  u16* WprojT= (u16*)(ws + (34u << 20));    //  2 MB: 1024x1024

  // --- precompute: transposed bf16 weights
  hipLaunchKernelGGL(transpose_bf16, dim3(32, 16), dim3(256), 0, stream, W_kv, WkvT, 1024, 2048);
  hipLaunchKernelGGL(transpose_bf16, dim3(16, 16), dim3(256), 0, stream, W_q, WqT, 1024, 1024);
  hipLaunchKernelGGL(transpose_bf16, dim3(16, 16), dim3(256), 0, stream, W_pos, WposT, 1024, 1024);
  hipLaunchKernelGGL(transpose_bf16, dim3(16, 16), dim3(256), 0, stream, W_proj, WprojT, 1024, 1024);

  // --- GEMMs (B^T form, A converted in-stage)
  hipLaunchKernelGGL((gemm_bt<float, u16>), dim3(16, 32), dim3(256), 0, stream,
                     full_in, WkvT, b_kv, kv, 4096, 2048, 1024);
  hipLaunchKernelGGL((gemm_bt<float, u16>), dim3(8, 16), dim3(256), 0, stream,
                     inputs, WqT, b_q, qq, 2048, 1024, 1024);
  hipLaunchKernelGGL((gemm_bt<float, u16>), dim3(8, 8), dim3(256), 0, stream,
                     pos_emb, WposT, b_pos, rr, 1024, 1024, 1024);
  // --- fused attention
  hipLaunchKernelGGL(flash_xl, dim3(8, 4, 16), dim3(256), 0, stream,
                     qq, kv, rr, u, v, av);
  // --- output projection
  hipLaunchKernelGGL((gemm_bt<u16, float>), dim3(8, 16), dim3(256), 0, stream,
                     av, WprojT, b_proj, out, 2048, 1024, 1024);
}

// Round 7
// 343.158 us; speedup vs baseline: 1.0123x; 1.0123x over previous
//
#include <hip/hip_runtime.h>

// AttentionXL (TransformerXL relative attention), MI355X gfx950.
// fp32 I/O. Pipeline: convert3 (bf16 activations) + transpose4 (bf16 W^T) ->
// 4x bf16 B^T-GEMM -> fused MFMA flash-XL (software-pipelined K-loop).
// Round 7: flash prefetch pipeline (grid-capped occupancy => spend VGPRs on
// latency hiding); GEMMs reverted to round-5 bf16-A form; dispatch merging.

typedef unsigned short u16;
typedef short short8 __attribute__((ext_vector_type(8)));
typedef float f32x4 __attribute__((ext_vector_type(4)));

#define BSZ 4
#define PREV 512

__device__ __forceinline__ float b2f(u16 u) {
  union { unsigned int i; float f; } x; x.i = ((unsigned int)u) << 16; return x.f;
}
__device__ __forceinline__ u16 f2b(float f) {
  union { float f; unsigned int i; } x; x.f = f;
  unsigned int u = x.i;
  return (u16)((u + 0x7fffu + ((u >> 16) & 1u)) >> 16);
}
__device__ __forceinline__ void storeC(u16* C, size_t idx, float v) { C[idx] = f2b(v); }
__device__ __forceinline__ void storeC(float* C, size_t idx, float v) { C[idx] = v; }

// ---------------------------------------------------------------------------
// 3 fp32->bf16 flat converts in one dispatch. Sizes: 4M / 2M / 1M elements.
// grid = 3584 blocks x 256 (2048 elements per block).
// ---------------------------------------------------------------------------
__global__ __launch_bounds__(256)
void convert3(const float* __restrict__ s0, const float* __restrict__ s1,
              const float* __restrict__ s2, u16* __restrict__ d0,
              u16* __restrict__ d1, u16* __restrict__ d2) {
  int bx = blockIdx.x;
  const float* s; u16* d; size_t base;
  if (bx < 2048)      { s = s0; d = d0; base = (size_t)bx * 2048; }
  else if (bx < 3072) { s = s1; d = d1; base = (size_t)(bx - 2048) * 2048; }
  else                { s = s2; d = d2; base = (size_t)(bx - 3072) * 2048; }
  size_t i = base + (size_t)threadIdx.x * 8;
  const f32x4* p = reinterpret_cast<const f32x4*>(s + i);
  f32x4 a = p[0], b = p[1];
  short8 r;
#pragma unroll
  for (int e = 0; e < 4; e++) { r[e] = (short)f2b(a[e]); r[e + 4] = (short)f2b(b[e]); }
  *reinterpret_cast<short8*>(d + i) = r;
}

// ---------------------------------------------------------------------------
// 4 weight transposes (fp32 W[K x N] -> bf16 WT[N x K]) in one dispatch.
// 64x64 tiles via LDS (pad 66). grid = (32, 16, 4); z selects matrix.
// ---------------------------------------------------------------------------
__global__ __launch_bounds__(256)
void transpose4(const float* __restrict__ W0, const float* __restrict__ W1,
                const float* __restrict__ W2, const float* __restrict__ W3,
                u16* __restrict__ T0, u16* __restrict__ T1,
                u16* __restrict__ T2, u16* __restrict__ T3) {
  const int z = blockIdx.z;
  const float* W; u16* T; int N;
  if (z == 0)      { W = W0; T = T0; N = 2048; }
  else if (z == 1) { W = W1; T = T1; N = 1024; }
  else if (z == 2) { W = W2; T = T2; N = 1024; }
  else             { W = W3; T = T3; N = 1024; }
  const int K = 1024;
  const int n0 = blockIdx.x * 64, k0 = blockIdx.y * 64;
  if (n0 >= N) return;

  __shared__ u16 ld[64 * 66];
  const int tid = threadIdx.x;
#pragma unroll
  for (int rep = 0; rep < 16; rep++) {
    int idx = tid + 256 * rep;
    int kk = idx >> 6, nn = idx & 63;
    ld[kk * 66 + nn] = f2b(W[(size_t)(k0 + kk) * N + n0 + nn]);
  }
  __syncthreads();
#pragma unroll
  for (int rep = 0; rep < 16; rep++) {
    int idx = tid + 256 * rep;
    int nn = idx >> 6, kk = idx & 63;
    T[(size_t)(n0 + nn) * K + k0 + kk] = ld[kk * 66 + nn];
  }
}

// ---------------------------------------------------------------------------
// GEMM (B^T form): C[M,N] = A[M,K] @ BT[N,K]^T + bias[N]. A, BT bf16
// k-contiguous; C fp32 or bf16. 128x128 tile, BK=64, 4 waves (2x2).
// ---------------------------------------------------------------------------
template <typename OT>
__global__ __launch_bounds__(256, 2)
void gemm_bt(const u16* __restrict__ A, const u16* __restrict__ BT,
             const float* __restrict__ bias, OT* __restrict__ C,
             int M, int N, int K)
{
  __shared__ __align__(16) short at[8192];  // [(mc*2+kc)][qd*16+mll][8]
  __shared__ __align__(16) short bt[8192];  // [(nc*2+kc)][qd*16+nl][8]

  const int tid = threadIdx.x;
  const int lane = tid & 63, w = tid >> 6;
  const int wr = w >> 1, wc = w & 1;
  const int quad = lane >> 4, ml = lane & 15;
  const int row0 = blockIdx.y * 128, col0 = blockIdx.x * 128;

  f32x4 acc[4][4];
  const f32x4 fzero = {0.f, 0.f, 0.f, 0.f};
#pragma unroll
  for (int i = 0; i < 4; i++)
#pragma unroll
    for (int j = 0; j < 4; j++) acc[i][j] = fzero;

  for (int k0 = 0; k0 < K; k0 += 64) {
    __syncthreads();
#pragma unroll
    for (int cc = 0; cc < 4; cc++) {
      int c = tid + 256 * cc;
      int m = c >> 3, oct = c & 7;
      short8 val = *reinterpret_cast<const short8*>(A + (size_t)(row0 + m) * K + k0 + oct * 8);
      int mc = m >> 4, mll = m & 15, kc = oct >> 2, qd = oct & 3;
      *reinterpret_cast<short8*>(at + (((mc * 2 + kc) * 64) + qd * 16 + mll) * 8) = val;
    }
#pragma unroll
    for (int cc = 0; cc < 4; cc++) {
      int c = tid + 256 * cc;
      int n = c >> 3, oct = c & 7;
      short8 val = *reinterpret_cast<const short8*>(BT + (size_t)(col0 + n) * K + k0 + oct * 8);
      int nc = n >> 4, nl = n & 15, kc = oct >> 2, qd = oct & 3;
      *reinterpret_cast<short8*>(bt + (((nc * 2 + kc) * 64) + qd * 16 + nl) * 8) = val;
    }
    __syncthreads();

    short8 af[4][2], bf[4][2];
#pragma unroll
    for (int mc = 0; mc < 4; mc++)
#pragma unroll
      for (int kc = 0; kc < 2; kc++)
        af[mc][kc] = *reinterpret_cast<const short8*>(at + ((((wr * 4 + mc) * 2 + kc) * 64) + lane) * 8);
#pragma unroll
    for (int nc = 0; nc < 4; nc++)
#pragma unroll
      for (int kc = 0; kc < 2; kc++)
        bf[nc][kc] = *reinterpret_cast<const short8*>(bt + ((((wc * 4 + nc) * 2 + kc) * 64) + lane) * 8);

#pragma unroll
    for (int mc = 0; mc < 4; mc++)
#pragma unroll
      for (int nc = 0; nc < 4; nc++)
#pragma unroll
        for (int kc = 0; kc < 2; kc++)
          acc[mc][nc] = __builtin_amdgcn_mfma_f32_16x16x32_bf16(af[mc][kc], bf[nc][kc], acc[mc][nc], 0, 0, 0);
  }

#pragma unroll
  for (int nc = 0; nc < 4; nc++) {
    int col = col0 + wc * 64 + nc * 16 + ml;
    float bv = bias[col];
#pragma unroll
    for (int mc = 0; mc < 4; mc++) {
#pragma unroll
      for (int reg = 0; reg < 4; reg++) {
        int row = row0 + wr * 64 + mc * 16 + quad * 4 + reg;
        storeC(C, (size_t)row * N + col, acc[mc][nc][reg] + bv);
      }
    }
  }
}

// ---------------------------------------------------------------------------
// Fused MFMA flash attention, TransformerXL relative position.
// Block = 256 (4 waves) per (i-tile 64, b, h); wave w owns rows i0+16w..+15.
// Software-pipelined K-loop: tile t+1's K/R fragments and V columns are
// prefetched into registers during tile t's compute (grid caps occupancy at
// 2 blocks/CU, so the VGPR budget for double-buffered fragments is free).
// V staged to dbuf LDS (b128 writes, one barrier/tile); pos2 strip spilled
// bf16 per-wave for the rel-shift diagonal gather; P via per-wave LDS.
// ---------------------------------------------------------------------------
__global__ __launch_bounds__(256, 2)
void flash_xl(const u16* __restrict__ q, const u16* __restrict__ kv,
              const u16* __restrict__ r, const float* __restrict__ u,
              const float* __restrict__ v, u16* __restrict__ av)
{
  __shared__ __align__(16) short vt[2][4096];  // [buf][kc(2)][quad(4)][d(64)][jj(8)]
  __shared__ u16 pos2w[4][16 * 84];            // per-wave pos2 (bf16), row stride 84
  __shared__ __align__(16) short pt[4][1024];  // per-wave P in A-frag order

  const int tid = threadIdx.x, lane = tid & 63, w = tid >> 6;
  const int quad = lane >> 4, ml = lane & 15;
  const int it = blockIdx.x, b = blockIdx.y, h = blockIdx.z;
  const int i0 = it * 64;

  const u16* kvK = kv + (size_t)b * 2048 + h * 64;          // + jg*8192 + d
  const u16* kvV = kv + (size_t)b * 2048 + 1024 + h * 64;
  const u16* rh  = r + h * 64;                               // + rel*1024 + d

  // Q fragments (A-operand): rows i0 + w*16 + ml, +u (content) / +v (position)
  short8 qu[2], qvf[2];
  {
    int ig = i0 + w * 16 + ml;
#pragma unroll
    for (int kc = 0; kc < 2; kc++) {
      int dbase = kc * 32 + quad * 8;
      short8 qq = *reinterpret_cast<const short8*>(q + ((size_t)ig * BSZ + b) * 1024 + h * 64 + dbase);
      const f32x4* up = reinterpret_cast<const f32x4*>(u + h * 64 + dbase);
      const f32x4* vp = reinterpret_cast<const f32x4*>(v + h * 64 + dbase);
      f32x4 u0 = up[0], u1 = up[1], v0 = vp[0], v1 = vp[1];
#pragma unroll
      for (int e = 0; e < 8; e++) {
        float qf = b2f((u16)qq[e]);
        float uu = (e < 4) ? u0[e] : u1[e - 4];
        float vv = (e < 4) ? v0[e] : v1[e - 4];
        qu[kc][e]  = (short)f2b(qf + uu);
        qvf[kc][e] = (short)f2b(qf + vv);
      }
    }
  }

  const f32x4 fzero = {0.f, 0.f, 0.f, 0.f};
  f32x4 o_acc[4];
#pragma unroll
  for (int i = 0; i < 4; i++) o_acc[i] = fzero;
  float m_run[4], l_run[4];
#pragma unroll
  for (int i = 0; i < 4; i++) { m_run[i] = -1e30f; l_run[i] = 0.f; }

  // ---- pipeline register state
  short8 kfA[4][2], rfA[5][2], kfB[4][2], rfB[5][2];
  short8 vg0, vg1;

  auto loadV = [&](int j0) {
#pragma unroll
    for (int s = 0; s < 8; s++)
      vg0[s] = (short)kvV[(size_t)(j0 + w * 16 + s) * 8192 + lane];
#pragma unroll
    for (int s = 0; s < 8; s++)
      vg1[s] = (short)kvV[(size_t)(j0 + w * 16 + 8 + s) * 8192 + lane];
  };
  auto writeV = [&](int buf) {
    const int kcw = w >> 1, qbase = (w & 1) * 2;
    *reinterpret_cast<short8*>(vt[buf] + ((kcw * 4 + qbase) * 64 + lane) * 8) = vg0;
    *reinterpret_cast<short8*>(vt[buf] + ((kcw * 4 + qbase + 1) * 64 + lane) * 8) = vg1;
  };
  auto loadK = [&](int j0, short8 kf[4][2]) {
#pragma unroll
    for (int nc = 0; nc < 4; nc++) {
      const u16* kp = kvK + (size_t)(j0 + nc * 16 + ml) * 8192;
#pragma unroll
      for (int kc = 0; kc < 2; kc++)
        kf[nc][kc] = *reinterpret_cast<const short8*>(kp + kc * 32 + quad * 8);
    }
  };
  auto loadR = [&](int t, short8 rf[5][2]) {
    const int relbase = t * 64 - i0 + 448;  // >= 0
#pragma unroll
    for (int nc2 = 0; nc2 < 5; nc2++) {
      int rel = relbase + ((3 - w) + nc2) * 16 + ml;
      if (rel > 1023) rel = 1023;  // masked region
      const u16* rp = rh + (size_t)rel * 1024;
#pragma unroll
      for (int kc = 0; kc < 2; kc++)
        rf[nc2][kc] = *reinterpret_cast<const short8*>(rp + kc * 32 + quad * 8);
    }
  };

  const int ntiles = it + 9;  // covers j <= i0+575 >= max valid j = i0+63+512

  // ---- prologue: tile 0 fully staged
  loadV(0);
  writeV(0);
  loadK(0, kfA);
  loadR(0, rfA);
  __syncthreads();

  for (int t = 0; t < ntiles; t++) {
    const int j0 = t * 64, buf = t & 1;
    const bool more = (t + 1) < ntiles;

    // ---- issue tile t+1's loads (latency hidden behind tile t's compute)
    if (more) {
      loadV(j0 + 64);
      loadK(j0 + 64, kfB);
      loadR(t + 1, rfB);
    }

    // ---- content scores from prefetched K fragments
    f32x4 sc[4];
#pragma unroll
    for (int nc = 0; nc < 4; nc++) {
      sc[nc] = fzero;
#pragma unroll
      for (int kc = 0; kc < 2; kc++)
        sc[nc] = __builtin_amdgcn_mfma_f32_16x16x32_bf16(qu[kc], kfA[nc][kc], sc[nc], 0, 0, 0);
    }
    // ---- position strip from prefetched R fragments
    f32x4 p2[5];
#pragma unroll
    for (int nc2 = 0; nc2 < 5; nc2++) {
      p2[nc2] = fzero;
#pragma unroll
      for (int kc = 0; kc < 2; kc++)
        p2[nc2] = __builtin_amdgcn_mfma_f32_16x16x32_bf16(qvf[kc], rfA[nc2][kc], p2[nc2], 0, 0, 0);
    }
    // spill pos2 (C layout) as bf16 for the row-dependent diagonal gather
#pragma unroll
    for (int nc2 = 0; nc2 < 5; nc2++)
#pragma unroll
      for (int reg = 0; reg < 4; reg++)
        pos2w[w][(quad * 4 + reg) * 84 + nc2 * 16 + ml] = f2b(p2[nc2][reg]);

    // ---- assemble S + mask + online softmax
    float pv_[4][4];
    float tmax[4] = {-1e30f, -1e30f, -1e30f, -1e30f};
#pragma unroll
    for (int nc = 0; nc < 4; nc++) {
      int jl = nc * 16 + ml;
#pragma unroll
      for (int reg = 0; reg < 4; reg++) {
        int rowl = quad * 4 + reg;
        int rrw = jl - rowl + 15;  // in [0,78]
        float s = sc[nc][reg] + b2f(pos2w[w][rowl * 84 + rrw]);
        s *= 0.125f;  // 1/sqrt(64)
        int ig = i0 + w * 16 + rowl;
        int jg = j0 + jl;
        if (jg > ig + PREV) s = -1e30f;
        pv_[nc][reg] = s;
        tmax[reg] = fmaxf(tmax[reg], s);
      }
    }
#pragma unroll
    for (int reg = 0; reg < 4; reg++) {
      float tm = tmax[reg];
#pragma unroll
      for (int off = 1; off < 16; off <<= 1) tm = fmaxf(tm, __shfl_xor(tm, off, 64));
      float mnew = fmaxf(m_run[reg], tm);
      float alpha = __expf(m_run[reg] - mnew);
      float rs = 0.f;
#pragma unroll
      for (int nc = 0; nc < 4; nc++) {
        float p = __expf(pv_[nc][reg] - mnew);
        pv_[nc][reg] = p;
        rs += p;
      }
#pragma unroll
      for (int off = 1; off < 16; off <<= 1) rs += __shfl_xor(rs, off, 64);
      l_run[reg] = l_run[reg] * alpha + rs;
      m_run[reg] = mnew;
#pragma unroll
      for (int nc = 0; nc < 4; nc++) o_acc[nc][reg] *= alpha;
    }

    // ---- P (C layout) -> bf16 A-frag via per-wave LDS transpose
#pragma unroll
    for (int nc = 0; nc < 4; nc++) {
      int jl = nc * 16 + ml;
      int kc = nc >> 1, qdj = (jl >> 3) & 3, jj = ml & 7;
#pragma unroll
      for (int reg = 0; reg < 4; reg++) {
        int rowl = quad * 4 + reg;
        pt[w][(kc * 64 + qdj * 16 + rowl) * 8 + jj] = (short)f2b(pv_[nc][reg]);
      }
    }
    short8 pf[2];
    pf[0] = *reinterpret_cast<const short8*>(pt[w] + (0 * 64 + lane) * 8);
    pf[1] = *reinterpret_cast<const short8*>(pt[w] + (1 * 64 + lane) * 8);

    // ---- PV accumulate: V B-frag from LDS (jl = kc*32 + quad*8 + jj)
#pragma unroll
    for (int ncd = 0; ncd < 4; ncd++)
#pragma unroll
      for (int kc = 0; kc < 2; kc++) {
        short8 vf = *reinterpret_cast<const short8*>(
            vt[buf] + ((kc * 4 + quad) * 64 + ncd * 16 + ml) * 8);
        o_acc[ncd] = __builtin_amdgcn_mfma_f32_16x16x32_bf16(pf[kc], vf, o_acc[ncd], 0, 0, 0);
      }

    // ---- commit tile t+1's V to its LDS buffer; rotate fragment registers
    if (more) {
      writeV(buf ^ 1);
#pragma unroll
      for (int nc = 0; nc < 4; nc++)
#pragma unroll
        for (int kc = 0; kc < 2; kc++) kfA[nc][kc] = kfB[nc][kc];
#pragma unroll
      for (int nc2 = 0; nc2 < 5; nc2++)
#pragma unroll
        for (int kc = 0; kc < 2; kc++) rfA[nc2][kc] = rfB[nc2][kc];
    }
    __syncthreads();
  }

  // ---- normalize and write attn_vec
  float inv[4];
#pragma unroll
  for (int reg = 0; reg < 4; reg++) inv[reg] = 1.0f / l_run[reg];
#pragma unroll
  for (int ncd = 0; ncd < 4; ncd++) {
#pragma unroll
    for (int reg = 0; reg < 4; reg++) {
      int rowl = quad * 4 + reg;
      int ig = i0 + w * 16 + rowl;
      av[((size_t)ig * BSZ + b) * 1024 + h * 64 + ncd * 16 + ml] = f2b(o_acc[ncd][reg] * inv[reg]);
    }
  }
}

// ---------------------------------------------------------------------------
extern "C" void kernel_launch(void* const* d_in, const int* in_sizes, int n_in,
                              void* d_out, int out_size, void* d_ws, size_t ws_size,
                              hipStream_t stream) {
  (void)in_sizes; (void)n_in; (void)out_size; (void)ws_size;

  const float* inputs  = (const float*)d_in[0];   // (512,4,1024)
  const float* pos_emb = (const float*)d_in[1];   // (1024,1,1024)
  const float* full_in = (const float*)d_in[2];   // (1024,4,1024)
  const float* u       = (const float*)d_in[3];   // (16,64)
  const float* v       = (const float*)d_in[4];   // (16,64)
  const float* W_kv    = (const float*)d_in[5];   // (1024,2048)
  const float* b_kv    = (const float*)d_in[6];   // (2048,)
  const float* W_q     = (const float*)d_in[7];   // (1024,1024)
  const float* b_q     = (const float*)d_in[8];
  const float* W_pos   = (const float*)d_in[9];   // (1024,1024)
  const float* b_pos   = (const float*)d_in[10];
  const float* W_proj  = (const float*)d_in[11];  // (1024,1024)
  const float* b_proj  = (const float*)d_in[12];
  // d_in[13] = mask (bool) — recomputed analytically (j > i + 512)
  float* out = (float*)d_out;

  char* ws = (char*)d_ws;
  u16* kv    = (u16*)(ws);                  // 16 MB: 4096x2048
  u16* qq    = (u16*)(ws + (16u << 20));    //  4 MB: 2048x1024
  u16* rr    = (u16*)(ws + (20u << 20));    //  2 MB: 1024x1024
  u16* av    = (u16*)(ws + (22u << 20));    //  4 MB: 2048x1024
  u16* fibf  = (u16*)(ws + (26u << 20));    //  8 MB: 4096x1024
  u16* inbf  = (u16*)(ws + (34u << 20));    //  4 MB: 2048x1024
  u16* pebf  = (u16*)(ws + (38u << 20));    //  2 MB: 1024x1024
  u16* WkvT  = (u16*)(ws + (40u << 20));    //  4 MB: 2048x1024
  u16* WqT   = (u16*)(ws + (44u << 20));    //  2 MB: 1024x1024
  u16* WposT = (u16*)(ws + (46u << 20));    //  2 MB: 1024x1024
  u16* WprojT= (u16*)(ws + (48u << 20));    //  2 MB: 1024x1024

  // --- precompute: bf16 activations (1 dispatch) + transposed weights (1)
  hipLaunchKernelGGL(convert3, dim3(3584), dim3(256), 0, stream,
                     full_in, inputs, pos_emb, fibf, inbf, pebf);
  hipLaunchKernelGGL(transpose4, dim3(32, 16, 4), dim3(256), 0, stream,
                     W_kv, W_q, W_pos, W_proj, WkvT, WqT, WposT, WprojT);

  // --- GEMMs (B^T form)
  hipLaunchKernelGGL((gemm_bt<u16>), dim3(16, 32), dim3(256), 0, stream,
                     fibf, WkvT, b_kv, kv, 4096, 2048, 1024);
  hipLaunchKernelGGL((gemm_bt<u16>), dim3(8, 16), dim3(256), 0, stream,
                     inbf, WqT, b_q, qq, 2048, 1024, 1024);
  hipLaunchKernelGGL((gemm_bt<u16>), dim3(8, 8), dim3(256), 0, stream,
                     pebf, WposT, b_pos, rr, 1024, 1024, 1024);
  // --- fused attention
  hipLaunchKernelGGL(flash_xl, dim3(8, 4, 16), dim3(256), 0, stream,
                     qq, kv, rr, u, v, av);
  // --- output projection
  hipLaunchKernelGGL((gemm_bt<float>), dim3(8, 16), dim3(256), 0, stream,
                     av, WprojT, b_proj, out, 2048, 1024, 1024);
}